// Round 3
// baseline (1092.857 us; speedup 1.0000x reference)
//
#include <hip/hip_runtime.h>
#include <hip/hip_bf16.h>
#include <math.h>

typedef __bf16 bf16x8 __attribute__((ext_vector_type(8)));
typedef __bf16 bf16x4 __attribute__((ext_vector_type(4)));
typedef float  f32x4  __attribute__((ext_vector_type(4)));

constexpr int D   = 128;
constexpr int LQ  = 2048;
constexpr int SK  = 2048;
constexpr int BM  = 256;  // queries per block (8 waves x 32 rows)
constexpr int BN  = 64;   // keys per iteration
constexpr int NKV = 16;   // B*H distinct KV heads
constexpr int NT  = SK / BN;  // 32

__device__ __forceinline__ void load_lds16(const void* g, void* l) {
  __builtin_amdgcn_global_load_lds((const __attribute__((address_space(1))) unsigned*)g,
                                   (__attribute__((address_space(3))) unsigned*)l, 16, 0, 0);
}

// ---- prologue A: K fp32 -> Khi/Klo bf16 (elementwise, coalesced)
__global__ __launch_bounds__(256) void conv_k(const float* __restrict__ k,
                                              __bf16* __restrict__ khi,
                                              __bf16* __restrict__ klo) {
  const size_t i = ((size_t)blockIdx.x * 256 + threadIdx.x) * 4;
  f32x4 a = *(const f32x4*)(k + i);
  bf16x4 hi, lo;
#pragma unroll
  for (int j = 0; j < 4; ++j) {
    hi[j] = (__bf16)a[j];
    lo[j] = (__bf16)(a[j] - (float)hi[j]);
  }
  *(bf16x4*)(khi + i) = hi;
  *(bf16x4*)(klo + i) = lo;
}

// ---- prologue B: V fp32 [bh][s][d] -> Vt bf16 [bh][d][s'] where s' is
// kappa-PERMUTED within each 32-key group: physical slot pi = 8q+4h+r holds
// key w = 16h+4q+r (q=0..3, h=0..1, r=0..3). This makes the PV A-fragment a
// single b128 read (keys {32t+16h+4quad+r} land contiguous per lane) with the
// round-0 conflict-free chunk pattern.
__global__ __launch_bounds__(256) void transpose_v(const float* __restrict__ v,
                                                   __bf16* __restrict__ vt) {
  const int b    = blockIdx.x;          // 1024 = 16 bh x 64
  const int bh   = b >> 6;
  const int t2   = (b & 63) * 256 + threadIdx.x;  // 0..16383 within bh
  const int d    = t2 & 127;
  const int slot = t2 >> 7;             // 0..127
  const int G    = slot >> 1;           // 32-key group 0..63
  const int h2   = slot & 1;            // which half of the group's slots
  const float* src = v + ((size_t)bh * SK + 32 * G) * D + d;
  bf16x8 o0, o1;
  // dst slot idx = 8*qq+4*h+r (pi = 16*h2 + idx, q = 2*h2+qq) <- key 16h+4q+r
#pragma unroll
  for (int qq = 0; qq < 2; ++qq)
#pragma unroll
    for (int h = 0; h < 2; ++h)
#pragma unroll
      for (int r = 0; r < 4; ++r) {
        const int idx = 8 * qq + 4 * h + r;
        const int w   = 16 * h + 4 * (2 * h2 + qq) + r;
        const __bf16 val = (__bf16)src[(size_t)w * D];
        if (idx < 8) o0[idx] = val; else o1[idx - 8] = val;
      }
  __bf16* dst = vt + ((size_t)bh * D + d) * SK + 32 * G + 16 * h2;
  *(bf16x8*)dst = o0;
  *(bf16x8*)(dst + 8) = o1;
}

// ---- main: flash GQA, 8 waves x 32 q-rows.
// LDS 80KB (= 2 blocks/CU, 4 waves/SIMD): Kh/Kl double-buffered (prefetch one
// tile ahead), Vs SINGLE-buffered (staged at iter top, consumed at iter end;
// guarded by counted vmcnt(4)+barrier so K prefetch stays in flight - T4).
// Swapped QK^T (mfma(K,Q)) => lane-local softmax; Q pre-scaled by log2e so
// softmax uses exp2f (saves the hidden x1.4427 mul per exp). T13 defer-max:
// skip O-rescale unless any row's max grew by >11.5 (log2 units; P<=2^11.5,
// bf16-safe). PV swapped with kappa k-slot permutation baked into global Vt
// => single b128 V-read per fragment, round-0 conflict-free pattern.
__global__ __launch_bounds__(512, 4)
void gqa_fwd(const float* __restrict__ qg, const __bf16* __restrict__ khi_g,
             const __bf16* __restrict__ klo_g, const __bf16* __restrict__ vt_g,
             float* __restrict__ outg)
{
  __shared__ alignas(16) __bf16 Kh[2][BN * D];   // 2 x 16KB
  __shared__ alignas(16) __bf16 Kl[2][BN * D];   // 2 x 16KB
  __shared__ alignas(16) __bf16 Vs[D * BN];      // 16KB   (total 80KB)

  // XCD swizzle: 512 blocks co-resident, 64 per XCD, each XCD 2 KV heads (~3MB L2).
  const int bid   = blockIdx.x;
  const int xcd   = bid & 7;
  const int idx   = bid >> 3;           // 0..63
  const int bh    = 2 * xcd + (idx & 1);
  const int grp   = (idx >> 1) & 3;
  const int qtile = idx >> 3;           // 0..7
  const int bhg   = bh * 4 + grp;

  const int tid  = threadIdx.x;
  const int wave = tid >> 6;            // 0..7
  const int lane = tid & 63;
  const int i16  = lane & 15;
  const int quad = lane >> 4;

  const float*  qbase = qg + (size_t)bhg * (LQ * D) + (size_t)(qtile * BM) * D;
  const __bf16* khb   = khi_g + (size_t)bh * (SK * D);
  const __bf16* klb   = klo_g + (size_t)bh * (SK * D);
  const __bf16* vtb   = vt_g + (size_t)bh * (D * SK);   // [d][s-permuted]

  // K: 4 x global_load_lds(16B)/wave, chunk-XOR source swizzle, linear dest
  auto stage_k = [&](int s0, int buf) {
#pragma unroll
    for (int c = 0; c < 2; ++c) {
      const int wc   = 2 * wave + c;          // chunk 0..15 (1KB each)
      const int srow = wc * 4 + (lane >> 4);  // 4 rows of 256B per chunk
      const int jk   = (lane & 15) ^ (srow & 15);
      load_lds16(khb + (size_t)(s0 + srow) * D + 8 * jk, (char*)&Kh[buf][0] + wc * 1024);
      load_lds16(klb + (size_t)(s0 + srow) * D + 8 * jk, (char*)&Kl[buf][0] + wc * 1024);
    }
  };
  // V: 2 x global_load_lds(16B)/wave into the single Vs buffer
  auto stage_v = [&](int s0) {
#pragma unroll
    for (int c = 0; c < 2; ++c) {
      const int wc   = 2 * wave + c;
      const int drow = wc * 8 + (lane >> 3);  // 8 rows of 128B per chunk
      const int jv   = (lane & 7) ^ (drow & 7);
      load_lds16(vtb + (size_t)drow * SK + s0 + 8 * jv, (char*)&Vs[0] + wc * 1024);
    }
  };

  // prologue staging (overlaps Q fragment load)
  stage_v(0);
  stage_k(0, 0);

  // ---- Q fragments, persistent hi/lo, pre-scaled by log2(e) for exp2 softmax
  constexpr float LOG2E = 1.44269504089f;
  bf16x8 qhi[2][4], qlo[2][4];
#pragma unroll
  for (int u = 0; u < 2; ++u) {
    const float* qp = qbase + (size_t)(32 * wave + 16 * u + i16) * D + 8 * quad;
#pragma unroll
    for (int t = 0; t < 4; ++t) {
      f32x4 a = *(const f32x4*)(qp + 32 * t);
      f32x4 b = *(const f32x4*)(qp + 32 * t + 4);
#pragma unroll
      for (int j = 0; j < 4; ++j) {
        const float a2 = a[j] * LOG2E;
        const float b2 = b[j] * LOG2E;
        qhi[u][t][j]     = (__bf16)a2;
        qlo[u][t][j]     = (__bf16)(a2 - (float)qhi[u][t][j]);
        qhi[u][t][j + 4] = (__bf16)b2;
        qlo[u][t][j + 4] = (__bf16)(b2 - (float)qhi[u][t][j + 4]);
      }
    }
  }

  f32x4 o_acc[2][8];
#pragma unroll
  for (int u = 0; u < 2; ++u)
#pragma unroll
    for (int c = 0; c < 8; ++c) o_acc[u][c] = (f32x4){0.f, 0.f, 0.f, 0.f};
  float m_r[2] = {-INFINITY, -INFINITY};
  float l_r[2] = {0.f, 0.f};

  asm volatile("s_waitcnt vmcnt(0)" ::: "memory");
  __syncthreads();

  for (int it = 0; it < NT; ++it) {
    const int cur = it & 1;
    const __bf16* khc = &Kh[cur][0];
    const __bf16* klc = &Kl[cur][0];

    // top staging: V for THIS tile first (oldest -> covered by vmcnt(4)),
    // then K for the NEXT tile (stays in flight across the pre-PV wait).
    if (it > 0) stage_v(it * BN);
    stage_k(((it + 1) & (NT - 1)) * BN, cur ^ 1);  // wrap: last iter re-stages t0 (benign)

    // ---- S^T = K Q^T (hi/lo bf16 split; swizzled LDS, conflict-free)
    f32x4 sf[2][4];
#pragma unroll
    for (int u = 0; u < 2; ++u)
#pragma unroll
      for (int n = 0; n < 4; ++n) sf[u][n] = (f32x4){0.f, 0.f, 0.f, 0.f};
#pragma unroll
    for (int n = 0; n < 4; ++n) {
#pragma unroll
      for (int t = 0; t < 4; ++t) {
        const int ke = (16 * n + i16) * 128 + 8 * ((4 * t + quad) ^ i16);
        bf16x8 kh = *(const bf16x8*)&khc[ke];
        bf16x8 kl = *(const bf16x8*)&klc[ke];
#pragma unroll
        for (int u = 0; u < 2; ++u) {
          sf[u][n] = __builtin_amdgcn_mfma_f32_16x16x32_bf16(kh, qhi[u][t], sf[u][n], 0, 0, 0);
          sf[u][n] = __builtin_amdgcn_mfma_f32_16x16x32_bf16(kh, qlo[u][t], sf[u][n], 0, 0, 0);
          sf[u][n] = __builtin_amdgcn_mfma_f32_16x16x32_bf16(kl, qhi[u][t], sf[u][n], 0, 0, 0);
        }
      }
    }
    // sf[u][n][r] = log2e * S[key=16n+4quad+r][query=32w+16u+i16]

    // ---- lane-local online softmax (log2 domain) + in-register P^T frags
    bf16x8 pb[2][2];
#pragma unroll
    for (int u = 0; u < 2; ++u) {
      const float ma = fmaxf(fmaxf(sf[u][0][0], sf[u][0][1]), fmaxf(sf[u][0][2], sf[u][0][3]));
      const float mb = fmaxf(fmaxf(sf[u][1][0], sf[u][1][1]), fmaxf(sf[u][1][2], sf[u][1][3]));
      const float mc = fmaxf(fmaxf(sf[u][2][0], sf[u][2][1]), fmaxf(sf[u][2][2], sf[u][2][3]));
      const float md = fmaxf(fmaxf(sf[u][3][0], sf[u][3][1]), fmaxf(sf[u][3][2], sf[u][3][3]));
      float mx = fmaxf(fmaxf(ma, mb), fmaxf(mc, md));
      mx = fmaxf(mx, __shfl_xor(mx, 16, 64));
      mx = fmaxf(mx, __shfl_xor(mx, 32, 64));
      // T13 defer-max: rescale only if some row grew by >11.5 (=8 nats).
      if (__any(mx > m_r[u] + 11.5f)) {
        const float mnew  = fmaxf(m_r[u], mx);
        const float alpha = exp2f(m_r[u] - mnew);   // first iter: exp2(-inf)=0
        m_r[u] = mnew;
        l_r[u] *= alpha;
#pragma unroll
        for (int c = 0; c < 8; ++c) o_acc[u][c] = o_acc[u][c] * alpha;
      }
      f32x4 rs4 = (f32x4){0.f, 0.f, 0.f, 0.f};
      // k-slot j of PV tile t holds key 32t+16(j>>2)+4quad+(j&3): lane-local.
#pragma unroll
      for (int t = 0; t < 2; ++t)
#pragma unroll
        for (int h = 0; h < 2; ++h)
#pragma unroll
          for (int r = 0; r < 4; ++r) {
            const float p   = exp2f(sf[u][2 * t + h][r] - m_r[u]);
            const __bf16 pv = (__bf16)p;
            pb[u][t][4 * h + r] = pv;
            rs4[r] += (float)pv;   // l consistent with bf16 P fed to P*V
          }
      float rs = (rs4[0] + rs4[1]) + (rs4[2] + rs4[3]);
      rs += __shfl_xor(rs, 16, 64);
      rs += __shfl_xor(rs, 32, 64);
      l_r[u] += rs;
    }

    // V staged this iter (oldest 2 loads) must have landed; K prefetch (4)
    // stays in flight. Barrier publishes all waves' V chunks.
    asm volatile("s_waitcnt vmcnt(4)" ::: "memory");
    __syncthreads();

    // ---- O^T += V^T P^T : single b128 per fragment (kappa baked into Vt)
#pragma unroll
    for (int c = 0; c < 8; ++c) {
      const int row = 16 * c + i16;
#pragma unroll
      for (int t = 0; t < 2; ++t) {
        bf16x8 av = *(const bf16x8*)&Vs[row * 64 + 8 * ((4 * t + quad) ^ (i16 & 7))];
#pragma unroll
        for (int u = 0; u < 2; ++u)
          o_acc[u][c] = __builtin_amdgcn_mfma_f32_16x16x32_bf16(av, pb[u][t], o_acc[u][c], 0, 0, 0);
      }
    }

    // drain K prefetch (landed long ago) and protect Vs overwrite next iter
    asm volatile("s_waitcnt vmcnt(0)" ::: "memory");
    __syncthreads();
  }

  // ---- epilogue: O^T accumulator -> contiguous f32x4 stores
  float* obase = outg + (size_t)bhg * (LQ * D) + (size_t)(qtile * BM) * D;
#pragma unroll
  for (int u = 0; u < 2; ++u) {
    const float inv = 1.f / l_r[u];
    float* op = obase + (size_t)(32 * wave + 16 * u + i16) * D;
#pragma unroll
    for (int c = 0; c < 8; ++c) {
      f32x4 r4 = o_acc[u][c] * inv;      // r component = d offset 4*quad+r
      *(f32x4*)(op + 16 * c + 4 * quad) = r4;
    }
  }
}

extern "C" void kernel_launch(void* const* d_in, const int* in_sizes, int n_in,
                              void* d_out, int out_size, void* d_ws, size_t ws_size,
                              hipStream_t stream) {
  const float* q = (const float*)d_in[0];
  const float* k = (const float*)d_in[1];
  const float* v = (const float*)d_in[2];
  float* out = (float*)d_out;
  (void)in_sizes; (void)n_in; (void)out_size; (void)ws_size;

  const size_t kv_elems = (size_t)NKV * SK * D;          // 4.19M
  __bf16* khi = (__bf16*)d_ws;                           // 8.39 MB
  __bf16* klo = khi + kv_elems;                          // 8.39 MB
  __bf16* vt  = klo + kv_elems;                          // 8.39 MB

  conv_k<<<dim3(kv_elems / (256 * 4)), 256, 0, stream>>>(k, khi, klo);
  transpose_v<<<dim3(NKV * 64), 256, 0, stream>>>(v, vt);
  gqa_fwd<<<dim3(8 * (LQ / BM) * 8), 512, 0, stream>>>(q, khi, klo, vt, out);
}

// Round 4
// 414.125 us; speedup vs baseline: 2.6390x; 2.6390x over previous
//
#include <hip/hip_runtime.h>
#include <hip/hip_bf16.h>
#include <math.h>

typedef __bf16 bf16x8 __attribute__((ext_vector_type(8)));
typedef __bf16 bf16x4 __attribute__((ext_vector_type(4)));
typedef float  f32x4  __attribute__((ext_vector_type(4)));

constexpr int D   = 128;
constexpr int LQ  = 2048;
constexpr int SK  = 2048;
constexpr int BM  = 256;  // queries per block (8 waves x 32 rows)
constexpr int BN  = 64;   // keys per iteration
constexpr int NKV = 16;   // B*H distinct KV heads
constexpr int NT  = SK / BN;  // 32

__device__ __forceinline__ void load_lds16(const void* g, void* l) {
  __builtin_amdgcn_global_load_lds((const __attribute__((address_space(1))) unsigned*)g,
                                   (__attribute__((address_space(3))) unsigned*)l, 16, 0, 0);
}

// ---- prologue A: K fp32 -> Khi/Klo bf16 (elementwise, coalesced)
__global__ __launch_bounds__(256) void conv_k(const float* __restrict__ k,
                                              __bf16* __restrict__ khi,
                                              __bf16* __restrict__ klo) {
  const size_t i = ((size_t)blockIdx.x * 256 + threadIdx.x) * 4;
  f32x4 a = *(const f32x4*)(k + i);
  bf16x4 hi, lo;
#pragma unroll
  for (int j = 0; j < 4; ++j) {
    hi[j] = (__bf16)a[j];
    lo[j] = (__bf16)(a[j] - (float)hi[j]);
  }
  *(bf16x4*)(khi + i) = hi;
  *(bf16x4*)(klo + i) = lo;
}

// ---- prologue B: V fp32 [bh][s][d] -> Vt bf16 [bh][d][s'] where s' is
// kappa-PERMUTED within each 32-key group: physical slot pi = 8q+4h+r holds
// key w = 16h+4q+r. PV A-fragment then = ONE b128 read with the round-0
// conflict-free chunk pattern (verified: 0 bank conflicts in round 3).
__global__ __launch_bounds__(256) void transpose_v(const float* __restrict__ v,
                                                   __bf16* __restrict__ vt) {
  const int b    = blockIdx.x;          // 1024 = 16 bh x 64
  const int bh   = b >> 6;
  const int t2   = (b & 63) * 256 + threadIdx.x;  // 0..16383 within bh
  const int d    = t2 & 127;
  const int slot = t2 >> 7;             // 0..127
  const int G    = slot >> 1;           // 32-key group 0..63
  const int h2   = slot & 1;            // which half of the group's slots
  const float* src = v + ((size_t)bh * SK + 32 * G) * D + d;
  bf16x8 o0, o1;
  // dst slot idx = 8*qq+4*h+r (pi = 16*h2 + idx, q = 2*h2+qq) <- key 16h+4q+r
#pragma unroll
  for (int qq = 0; qq < 2; ++qq)
#pragma unroll
    for (int h = 0; h < 2; ++h)
#pragma unroll
      for (int r = 0; r < 4; ++r) {
        const int idx = 8 * qq + 4 * h + r;
        const int w   = 16 * h + 4 * (2 * h2 + qq) + r;
        const __bf16 val = (__bf16)src[(size_t)w * D];
        if (idx < 8) o0[idx] = val; else o1[idx - 8] = val;
      }
  __bf16* dst = vt + ((size_t)bh * D + d) * SK + 32 * G + 16 * h2;
  *(bf16x8*)dst = o0;
  *(bf16x8*)(dst + 8) = o1;
}

// ---- main: flash GQA, 8 waves x 32 q-rows. Round-2 envelope:
// __launch_bounds__(512,2) (reg cap 256: NO spills; round-3's (512,4) forced
// 128-reg cap -> 4GB scratch traffic), double-buffered Kh/Kl/Vs (96KB LDS),
// prefetch-one-tile-ahead, ONE vmcnt(0)+barrier per iter.
// Kept from round 3 (both verified): kappa-baked Vt -> conflict-free b128 PV
// reads; exp2-domain softmax (Q pre-scaled by log2e) + T13 defer-max.
// Added: T5 s_setprio(1) around MFMA clusters.
__global__ __launch_bounds__(512, 2)
void gqa_fwd(const float* __restrict__ qg, const __bf16* __restrict__ khi_g,
             const __bf16* __restrict__ klo_g, const __bf16* __restrict__ vt_g,
             float* __restrict__ outg)
{
  __shared__ alignas(16) __bf16 Kh[2][BN * D];   // 2 x 16KB
  __shared__ alignas(16) __bf16 Kl[2][BN * D];   // 2 x 16KB
  __shared__ alignas(16) __bf16 Vs[2][D * BN];   // 2 x 16KB  (total 96KB)

  // XCD swizzle: 64 blocks per XCD, each XCD owns 2 KV heads (~3MB L2 set).
  const int bid   = blockIdx.x;
  const int xcd   = bid & 7;
  const int idx   = bid >> 3;           // 0..63
  const int bh    = 2 * xcd + (idx & 1);
  const int grp   = (idx >> 1) & 3;
  const int qtile = idx >> 3;           // 0..7
  const int bhg   = bh * 4 + grp;

  const int tid  = threadIdx.x;
  const int wave = tid >> 6;            // 0..7
  const int lane = tid & 63;
  const int i16  = lane & 15;
  const int quad = lane >> 4;

  const float*  qbase = qg + (size_t)bhg * (LQ * D) + (size_t)(qtile * BM) * D;
  const __bf16* khb   = khi_g + (size_t)bh * (SK * D);
  const __bf16* klb   = klo_g + (size_t)bh * (SK * D);
  const __bf16* vtb   = vt_g + (size_t)bh * (D * SK);   // [d][s-permuted]

  // per-wave staging: 6 x global_load_lds(16B), src-swizzled, linear dest
  auto stage = [&](int s0, int buf) {
#pragma unroll
    for (int c = 0; c < 2; ++c) {
      const int wc   = 2 * wave + c;          // chunk 0..15 (1KB each)
      const int srow = wc * 4 + (lane >> 4);  // K: 4 rows of 256B per chunk
      const int jk   = (lane & 15) ^ (srow & 15);
      load_lds16(khb + (size_t)(s0 + srow) * D + 8 * jk, (char*)&Kh[buf][0] + wc * 1024);
      load_lds16(klb + (size_t)(s0 + srow) * D + 8 * jk, (char*)&Kl[buf][0] + wc * 1024);
      const int drow = wc * 8 + (lane >> 3);  // V: 8 rows of 128B per chunk
      const int jv   = (lane & 7) ^ (drow & 7);
      load_lds16(vtb + (size_t)drow * SK + s0 + 8 * jv, (char*)&Vs[buf][0] + wc * 1024);
    }
  };

  // prologue: stage tile 0 into buf 0 (overlaps the Q-fragment load below)
  stage(0, 0);

  // ---- Q fragments, persistent hi/lo, pre-scaled by log2(e) for exp2 softmax
  constexpr float LOG2E = 1.44269504089f;
  bf16x8 qhi[2][4], qlo[2][4];
#pragma unroll
  for (int u = 0; u < 2; ++u) {
    const float* qp = qbase + (size_t)(32 * wave + 16 * u + i16) * D + 8 * quad;
#pragma unroll
    for (int t = 0; t < 4; ++t) {
      f32x4 a = *(const f32x4*)(qp + 32 * t);
      f32x4 b = *(const f32x4*)(qp + 32 * t + 4);
#pragma unroll
      for (int j = 0; j < 4; ++j) {
        const float a2 = a[j] * LOG2E;
        const float b2 = b[j] * LOG2E;
        qhi[u][t][j]     = (__bf16)a2;
        qlo[u][t][j]     = (__bf16)(a2 - (float)qhi[u][t][j]);
        qhi[u][t][j + 4] = (__bf16)b2;
        qlo[u][t][j + 4] = (__bf16)(b2 - (float)qhi[u][t][j + 4]);
      }
    }
  }

  f32x4 o_acc[2][8];
#pragma unroll
  for (int u = 0; u < 2; ++u)
#pragma unroll
    for (int c = 0; c < 8; ++c) o_acc[u][c] = (f32x4){0.f, 0.f, 0.f, 0.f};
  float m_r[2] = {-INFINITY, -INFINITY};
  float l_r[2] = {0.f, 0.f};

  asm volatile("s_waitcnt vmcnt(0)" ::: "memory");
  __syncthreads();

  for (int it = 0; it < NT; ++it) {
    const int cur = it & 1;
    const __bf16* khc = &Kh[cur][0];
    const __bf16* klc = &Kl[cur][0];
    const __bf16* vsc = &Vs[cur][0];

    // issue next tile's staging FIRST; latency hides under compute
    if (it + 1 < NT) stage((it + 1) * BN, cur ^ 1);

    // ---- S^T = K Q^T (hi/lo bf16 split; swizzled LDS, conflict-free)
    f32x4 sf[2][4];
#pragma unroll
    for (int u = 0; u < 2; ++u)
#pragma unroll
      for (int n = 0; n < 4; ++n) sf[u][n] = (f32x4){0.f, 0.f, 0.f, 0.f};
    __builtin_amdgcn_s_setprio(1);
#pragma unroll
    for (int n = 0; n < 4; ++n) {
#pragma unroll
      for (int t = 0; t < 4; ++t) {
        const int ke = (16 * n + i16) * 128 + 8 * ((4 * t + quad) ^ i16);
        bf16x8 kh = *(const bf16x8*)&khc[ke];
        bf16x8 kl = *(const bf16x8*)&klc[ke];
#pragma unroll
        for (int u = 0; u < 2; ++u) {
          sf[u][n] = __builtin_amdgcn_mfma_f32_16x16x32_bf16(kh, qhi[u][t], sf[u][n], 0, 0, 0);
          sf[u][n] = __builtin_amdgcn_mfma_f32_16x16x32_bf16(kh, qlo[u][t], sf[u][n], 0, 0, 0);
          sf[u][n] = __builtin_amdgcn_mfma_f32_16x16x32_bf16(kl, qhi[u][t], sf[u][n], 0, 0, 0);
        }
      }
    }
    __builtin_amdgcn_s_setprio(0);
    // sf[u][n][r] = log2e * S[key=16n+4quad+r][query=32w+16u+i16]

    // ---- lane-local online softmax (log2 domain) + in-register P^T frags
    bf16x8 pb[2][2];
#pragma unroll
    for (int u = 0; u < 2; ++u) {
      const float ma = fmaxf(fmaxf(sf[u][0][0], sf[u][0][1]), fmaxf(sf[u][0][2], sf[u][0][3]));
      const float mb = fmaxf(fmaxf(sf[u][1][0], sf[u][1][1]), fmaxf(sf[u][1][2], sf[u][1][3]));
      const float mc = fmaxf(fmaxf(sf[u][2][0], sf[u][2][1]), fmaxf(sf[u][2][2], sf[u][2][3]));
      const float md = fmaxf(fmaxf(sf[u][3][0], sf[u][3][1]), fmaxf(sf[u][3][2], sf[u][3][3]));
      float mx = fmaxf(fmaxf(ma, mb), fmaxf(mc, md));
      mx = fmaxf(mx, __shfl_xor(mx, 16, 64));
      mx = fmaxf(mx, __shfl_xor(mx, 32, 64));
      // T13 defer-max: rescale only if some row grew by >11.5 (=8 nats).
      if (__any(mx > m_r[u] + 11.5f)) {
        const float mnew  = fmaxf(m_r[u], mx);
        const float alpha = exp2f(m_r[u] - mnew);   // first iter: exp2(-inf)=0
        m_r[u] = mnew;
        l_r[u] *= alpha;
#pragma unroll
        for (int c = 0; c < 8; ++c) o_acc[u][c] = o_acc[u][c] * alpha;
      }
      f32x4 rs4 = (f32x4){0.f, 0.f, 0.f, 0.f};
      // k-slot j of PV tile t holds key 32t+16(j>>2)+4quad+(j&3): lane-local.
#pragma unroll
      for (int t = 0; t < 2; ++t)
#pragma unroll
        for (int h = 0; h < 2; ++h)
#pragma unroll
          for (int r = 0; r < 4; ++r) {
            const float p   = exp2f(sf[u][2 * t + h][r] - m_r[u]);
            const __bf16 pv = (__bf16)p;
            pb[u][t][4 * h + r] = pv;
            rs4[r] += (float)pv;   // l consistent with bf16 P fed to P*V
          }
      float rs = (rs4[0] + rs4[1]) + (rs4[2] + rs4[3]);
      rs += __shfl_xor(rs, 16, 64);
      rs += __shfl_xor(rs, 32, 64);
      l_r[u] += rs;
    }

    // ---- O^T += V^T P^T : single b128 per fragment (kappa baked into Vt)
    __builtin_amdgcn_s_setprio(1);
#pragma unroll
    for (int c = 0; c < 8; ++c) {
      const int row = 16 * c + i16;
#pragma unroll
      for (int t = 0; t < 2; ++t) {
        bf16x8 av = *(const bf16x8*)&vsc[row * 64 + 8 * ((4 * t + quad) ^ (i16 & 7))];
#pragma unroll
        for (int u = 0; u < 2; ++u)
          o_acc[u][c] = __builtin_amdgcn_mfma_f32_16x16x32_bf16(av, pb[u][t], o_acc[u][c], 0, 0, 0);
      }
    }
    __builtin_amdgcn_s_setprio(0);

    // staging for tile it+1 has had a full compute phase to land
    asm volatile("s_waitcnt vmcnt(0)" ::: "memory");
    __syncthreads();
  }

  // ---- epilogue: O^T accumulator -> contiguous f32x4 stores
  float* obase = outg + (size_t)bhg * (LQ * D) + (size_t)(qtile * BM) * D;
#pragma unroll
  for (int u = 0; u < 2; ++u) {
    const float inv = 1.f / l_r[u];
    float* op = obase + (size_t)(32 * wave + 16 * u + i16) * D;
#pragma unroll
    for (int c = 0; c < 8; ++c) {
      f32x4 r4 = o_acc[u][c] * inv;      // r component = d offset 4*quad+r
      *(f32x4*)(op + 16 * c + 4 * quad) = r4;
    }
  }
}

extern "C" void kernel_launch(void* const* d_in, const int* in_sizes, int n_in,
                              void* d_out, int out_size, void* d_ws, size_t ws_size,
                              hipStream_t stream) {
  const float* q = (const float*)d_in[0];
  const float* k = (const float*)d_in[1];
  const float* v = (const float*)d_in[2];
  float* out = (float*)d_out;
  (void)in_sizes; (void)n_in; (void)out_size; (void)ws_size;

  const size_t kv_elems = (size_t)NKV * SK * D;          // 4.19M
  __bf16* khi = (__bf16*)d_ws;                           // 8.39 MB
  __bf16* klo = khi + kv_elems;                          // 8.39 MB
  __bf16* vt  = klo + kv_elems;                          // 8.39 MB

  conv_k<<<dim3(kv_elems / (256 * 4)), 256, 0, stream>>>(k, khi, klo);
  transpose_v<<<dim3(NKV * 64), 256, 0, stream>>>(v, vt);
  gqa_fwd<<<dim3(8 * (LQ / BM) * 8), 512, 0, stream>>>(q, khi, klo, vt, out);
}